// Round 15
// baseline (902.111 us; speedup 1.0000x reference)
//
#include <hip/hip_runtime.h>
#include <cstdint>
#include <cstddef>

// Problem constants
#define BB 4
#define SS 4096
#define DD 256
#define SCORE_SCALE (1.0f/16.0f)   // 1/sqrt(256)
#define PIW 0.5f
#define NROWS (BB * SS)            // 16384 flattened rows

typedef float          f32x4  __attribute__((ext_vector_type(4)));
typedef __bf16         bf16v8 __attribute__((ext_vector_type(8)));
typedef unsigned short u16v8  __attribute__((ext_vector_type(8)));
typedef unsigned short u16v4  __attribute__((ext_vector_type(4)));

__device__ __forceinline__ f32x4 mfma_bf16(u16v8 a, u16v8 b, f32x4 c) {
    return __builtin_amdgcn_mfma_f32_16x16x32_bf16(
        __builtin_bit_cast(bf16v8, a), __builtin_bit_cast(bf16v8, b), c, 0, 0, 0);
}

__device__ __forceinline__ unsigned short f2bf(float f) {
    unsigned u = __float_as_uint(f);
    u += 0x7FFFu + ((u >> 16) & 1u);           // RNE (inputs finite)
    return (unsigned short)(u >> 16);
}
__device__ __forceinline__ float bf2f(unsigned short h) {
    return __uint_as_float(((unsigned)h) << 16);
}
__device__ __forceinline__ unsigned fenc(float x) {
    unsigned u = __float_as_uint(x);
    return (u & 0x80000000u) ? ~u : (u | 0x80000000u);
}
__device__ __forceinline__ float fdec(unsigned e) {
    return __uint_as_float((e & 0x80000000u) ? (e ^ 0x80000000u) : ~e);
}

// MFMA-fragment-order index for a [row][k] bf16 element (16-row x 32-k tiles):
// frag[tile = row>>4][kk = k>>5][lane = (row&15)|(((k>>3)&3)<<4)][e = k&7]
// A wave's fragment load (fixed tile,kk; lane 0..63; e 0..7) is 1KB contiguous.
__device__ __forceinline__ size_t fragidx(int growFlat, int k, int kPerRow32) {
    return ((((size_t)(growFlat >> 4) * kPerRow32 + (k >> 5)) * 64)
            + ((growFlat & 15) | (((k >> 3) & 3) << 4))) * 8 + (k & 7);
}

// ---------------------------------------------------------------------------
// Projections via split-bf16 MFMA (Ah*Wh + Ah*Wl + Al*Wh ~ fp32 precision):
// C = A[16384,256] @ W[256,256]. 128x128 tile, 4 waves (2x2 of 64x64), BK=32.
// z=0: qh/ql bf16 split, FRAGMENT ORDER. z=1: kh/kl same. z=2: vfrag.
// Also inits gmax.  (round-12 proven version)
// ---------------------------------------------------------------------------
#define PSPAD 42   // 32 + 10 u16 row stride (W-transpose staging conflicts)

__global__ __launch_bounds__(256) void proj_kernel(
    const float* __restrict__ query, const float* __restrict__ key_, const float* __restrict__ value,
    const float* __restrict__ Wq, const float* __restrict__ Wk, const float* __restrict__ Wv,
    unsigned short* __restrict__ qh, unsigned short* __restrict__ ql,
    unsigned short* __restrict__ kh, unsigned short* __restrict__ kl,
    unsigned short* __restrict__ vT, unsigned* __restrict__ gmax)
{
    const int z = blockIdx.z;
    const float* A = (z == 0) ? query : (z == 1) ? key_ : value;
    const float* W = (z == 0) ? Wq    : (z == 1) ? Wk   : Wv;
    if (z == 0 && blockIdx.x == 0 && blockIdx.y == 0 && threadIdx.x == 0)
        *gmax = 0x007FFFFFu;   // fenc(-inf)

    __shared__ unsigned short Ah[128][PSPAD];
    __shared__ unsigned short Al[128][PSPAD];
    __shared__ unsigned short Bh[128][PSPAD];   // W^T split: [n][k]
    __shared__ unsigned short Bl[128][PSPAD];

    const int tid = threadIdx.x;
    const int lane = tid & 63, w = tid >> 6;
    const int wr = (w >> 1) * 64, wc = (w & 1) * 64;
    const int m = lane & 15, qq = lane >> 4;
    const int rowBase = blockIdx.y * 128;   // flattened B*S row
    const int colBase = blockIdx.x * 128;

    f32x4 acc[4][4];
    #pragma unroll
    for (int i = 0; i < 4; i++)
        #pragma unroll
        for (int j = 0; j < 4; j++)
            acc[i][j] = (f32x4){0.f, 0.f, 0.f, 0.f};

    const int chunk = (tid & 3) * 8;   // float offset within 32-wide k-slab
    const int srow  = tid >> 2;        // 0..63

    for (int k0 = 0; k0 < DD; k0 += 32) {
        // A staging: rows srow, srow+64; 8 fp32 -> bf16 h/l
        #pragma unroll
        for (int i = 0; i < 2; i++) {
            int r = srow + i * 64;
            const float* src = &A[(size_t)(rowBase + r) * DD + k0 + chunk];
            float4 f0 = *(const float4*)src;
            float4 f1 = *(const float4*)(src + 4);
            float v[8] = {f0.x, f0.y, f0.z, f0.w, f1.x, f1.y, f1.z, f1.w};
            u16v8 h, l;
            #pragma unroll
            for (int e = 0; e < 8; e++) {
                h[e] = f2bf(v[e]);
                l[e] = f2bf(v[e] - bf2f(h[e]));
            }
            *(u16v8*)&Ah[r][chunk] = h;
            *(u16v8*)&Al[r][chunk] = l;
        }
        // W staging transposed: W[k0+kk][colBase+n] -> Bh/Bl[n][kk]
        #pragma unroll
        for (int i = 0; i < 4; i++) {
            int idx = tid + i * 256;
            int kk = idx >> 5, nq = idx & 31;
            float4 f = *(const float4*)&W[(size_t)(k0 + kk) * DD + colBase + nq * 4];
            float v[4] = {f.x, f.y, f.z, f.w};
            #pragma unroll
            for (int e = 0; e < 4; e++) {
                unsigned short h = f2bf(v[e]);
                unsigned short l = f2bf(v[e] - bf2f(h));
                Bh[nq * 4 + e][kk] = h;
                Bl[nq * 4 + e][kk] = l;
            }
        }
        __syncthreads();

        const int kb = qq * 8;
        u16v8 ah[4], al[4], bh[4], bl[4];
        #pragma unroll
        for (int i = 0; i < 4; i++) {
            ah[i] = *(const u16v8*)&Ah[wr + i * 16 + m][kb];
            al[i] = *(const u16v8*)&Al[wr + i * 16 + m][kb];
            bh[i] = *(const u16v8*)&Bh[wc + i * 16 + m][kb];
            bl[i] = *(const u16v8*)&Bl[wc + i * 16 + m][kb];
        }
        #pragma unroll
        for (int i = 0; i < 4; i++)
            #pragma unroll
            for (int j = 0; j < 4; j++) {
                acc[i][j] = mfma_bf16(ah[i], bh[j], acc[i][j]);
                acc[i][j] = mfma_bf16(ah[i], bl[j], acc[i][j]);
                acc[i][j] = mfma_bf16(al[i], bh[j], acc[i][j]);
            }
        __syncthreads();
    }

    // epilogue: lane (m,qq) holds C[rowBase+wr+i*16+qq*4+r][colBase+wc+j*16+m]
    #pragma unroll
    for (int i = 0; i < 4; i++) {
        #pragma unroll
        for (int j = 0; j < 4; j++) {
            #pragma unroll
            for (int r = 0; r < 4; r++) {
                const int gr  = rowBase + wr + i * 16 + qq * 4 + r;
                const int col = colBase + wc + j * 16 + m;
                const float v = acc[i][j][r];
                if (z == 2) {
                    const int b2 = gr >> 12, s2 = gr & (SS - 1);
                    size_t idx = (size_t)b2 * (16 * 128 * 512)
                               + fragidx(col, s2, 128);
                    vT[idx] = f2bf(v);
                } else {
                    unsigned short h = f2bf(v);
                    unsigned short l = f2bf(v - bf2f(h));
                    unsigned short* H = (z == 0) ? qh : kh;
                    unsigned short* L = (z == 0) ? ql : kl;
                    size_t idx = fragidx(gr, col, 8);   // tiles over B*S rows
                    H[idx] = h;
                    L[idx] = l;
                }
            }
        }
    }
}

// ---------------------------------------------------------------------------
// Scores: C = (q@k^T)/16 via split-bf16 MFMA: qh*kh + qh*kl + ql*kh.
// 128x128 C-tile, 4 waves (2x2 of 64x64). Fragment-order panels: coalesced
// 1KB wave loads straight from the L2-resident panels — NO LDS staging, NO
// K-loop barriers, compiler-scheduled (round-12 proven). Epilogue: per-row
// tile stats -> tmaxg/tsumg, block max -> gmax, then nt C-stores last.
// ---------------------------------------------------------------------------
__global__ __launch_bounds__(256) void scores_mfma(
    const unsigned short* __restrict__ qh, const unsigned short* __restrict__ ql,
    const unsigned short* __restrict__ kh, const unsigned short* __restrict__ kl,
    float* __restrict__ attn, unsigned* __restrict__ gmax,
    float* __restrict__ tmaxg, float* __restrict__ tsumg)
{
    // XCD decode: block i -> XCD i%8; batch b owns XCDs {2b,2b+1}
    const int lin = blockIdx.x;
    const int b = (lin & 7) >> 1;
    const int t2 = ((lin >> 3) << 1) | (lin & 1);   // 0..1023
    const int bx = t2 & 31, by = t2 >> 5;
    const int rowBase = by * 128;
    const int colBase = bx * 128;

    float* C = attn + (size_t)b * SS * SS;

    __shared__ float s_m[4][64];
    __shared__ float s_s[4][64];
    __shared__ float red[128];

    const int tid = threadIdx.x;
    const int lane = tid & 63, w = tid >> 6;
    const int wr = (w >> 1) * 64, wc = (w & 1) * 64;
    const int m = lane & 15, qq = lane >> 4;

    f32x4 acc[4][4];
    #pragma unroll
    for (int i = 0; i < 4; i++)
        #pragma unroll
        for (int j = 0; j < 4; j++)
            acc[i][j] = (f32x4){0.f, 0.f, 0.f, 0.f};

    const size_t ta = ((size_t)b * SS + rowBase + wr) >> 4;
    const size_t tb = ((size_t)b * SS + colBase + wc) >> 4;

    #pragma unroll 2
    for (int kk = 0; kk < 8; kk++) {
        u16v8 ah[4], al[4], bh[4], bl[4];
        #pragma unroll
        for (int i = 0; i < 4; i++) {
            const size_t fa = (((ta + i) * 8 + kk) * 64 + lane) * 8;
            const size_t fb = (((tb + i) * 8 + kk) * 64 + lane) * 8;
            ah[i] = *(const u16v8*)&qh[fa];   // 1KB coalesced per wave
            al[i] = *(const u16v8*)&ql[fa];
            bh[i] = *(const u16v8*)&kh[fb];
            bl[i] = *(const u16v8*)&kl[fb];
        }
        #pragma unroll
        for (int i = 0; i < 4; i++)
            #pragma unroll
            for (int j = 0; j < 4; j++) {
                acc[i][j] = mfma_bf16(ah[i], bh[j], acc[i][j]);
                acc[i][j] = mfma_bf16(ah[i], bl[j], acc[i][j]);
                acc[i][j] = mfma_bf16(al[i], bh[j], acc[i][j]);
            }
    }

    // scale once; all consumers (stats, gmax, C store) use scaled values
    #pragma unroll
    for (int i = 0; i < 4; i++)
        #pragma unroll
        for (int j = 0; j < 4; j++)
            acc[i][j] *= SCORE_SCALE;

    // ---- per-row tile stats (flash-style), register resident ----
    float lmax[16];
    #pragma unroll
    for (int i = 0; i < 4; i++)
        #pragma unroll
        for (int r = 0; r < 4; r++)
            lmax[i * 4 + r] = fmaxf(fmaxf(acc[i][0][r], acc[i][1][r]),
                                    fmaxf(acc[i][2][r], acc[i][3][r]));
    #pragma unroll
    for (int t = 0; t < 16; t++) {
        #pragma unroll
        for (int msk = 1; msk < 16; msk <<= 1)
            lmax[t] = fmaxf(lmax[t], __shfl_xor(lmax[t], msk));
    }
    if (m == 0) {
        #pragma unroll
        for (int i = 0; i < 4; i++)
            #pragma unroll
            for (int r = 0; r < 4; r++)
                s_m[w][i * 16 + qq * 4 + r] = lmax[i * 4 + r];
    }
    __syncthreads();
    float lsum[16];
    #pragma unroll
    for (int i = 0; i < 4; i++)
        #pragma unroll
        for (int r = 0; r < 4; r++) {
            int idx = i * 16 + qq * 4 + r;
            float rm = fmaxf(s_m[w][idx], s_m[w ^ 1][idx]);
            float s = 0.f;
            #pragma unroll
            for (int j = 0; j < 4; j++)
                s += __expf(acc[i][j][r] - rm);
            lsum[i * 4 + r] = s;
        }
    #pragma unroll
    for (int t = 0; t < 16; t++) {
        #pragma unroll
        for (int msk = 1; msk < 16; msk <<= 1)
            lsum[t] += __shfl_xor(lsum[t], msk);
    }
    if (m == 0) {
        #pragma unroll
        for (int i = 0; i < 4; i++)
            #pragma unroll
            for (int r = 0; r < 4; r++)
                s_s[w][i * 16 + qq * 4 + r] = lsum[i * 4 + r];
    }
    __syncthreads();

    if (tid < 128) {
        int wp = tid >> 6, lr = tid & 63;
        float tm = fmaxf(s_m[2 * wp][lr], s_m[2 * wp + 1][lr]);
        float ts = s_s[2 * wp][lr] + s_s[2 * wp + 1][lr];   // same reference max
        size_t gi = (size_t)bx * NROWS + (size_t)b * SS + rowBase + tid;
        tmaxg[gi] = tm;
        tsumg[gi] = ts;
        red[tid] = tm;
    }
    __syncthreads();
    for (int s2 = 64; s2 > 0; s2 >>= 1) {
        if (tid < s2) red[tid] = fmaxf(red[tid], red[tid + s2]);
        __syncthreads();
    }
    if (tid == 0) atomicMax(gmax, fenc(red[0]));

    // store raw scores LAST (nt stream; no barrier after -> no drain stall)
    #pragma unroll
    for (int i = 0; i < 4; i++)
        #pragma unroll
        for (int j = 0; j < 4; j++)
            #pragma unroll
            for (int r = 0; r < 4; r++) {
                int row = rowBase + wr + i * 16 + qq * 4 + r;
                int col = colBase + wc + j * 16 + m;
                __builtin_nontemporal_store(acc[i][j][r], &C[(size_t)row * SS + col]);
            }
}

// ---------------------------------------------------------------------------
// Merge per-tile stats into per-row (max, 1/sum), folding in the diag bias
// (needs final gmax). Reads 4 MB stats + 16K diag elements. Tiny.
// ---------------------------------------------------------------------------
__global__ __launch_bounds__(256) void stats_merge(
    const float* __restrict__ tmaxg, const float* __restrict__ tsumg,
    const float* __restrict__ attn, const unsigned* __restrict__ gmax,
    float* __restrict__ rowm, float* __restrict__ rowinv)
{
    const int grow = blockIdx.x * 256 + threadIdx.x;   // 0..16383
    const int b = grow >> 12, i = grow & (SS - 1);
    const float bias = PIW * fdec(*gmax);

    float tm[32];
    float mx = -INFINITY;
    #pragma unroll
    for (int t = 0; t < 32; t++) {
        tm[t] = tmaxg[(size_t)t * NROWS + grow];
        mx = fmaxf(mx, tm[t]);
    }
    const float dii = attn[(size_t)b * SS * SS + (size_t)i * SS + i];
    mx = fmaxf(mx, dii + bias);

    float s = 0.f;
    #pragma unroll
    for (int t = 0; t < 32; t++)
        s += tsumg[(size_t)t * NROWS + grow] * __expf(tm[t] - mx);
    // replace unbiased diag contribution with biased one
    s += __expf(dii + bias - mx) - __expf(dii - mx);

    rowm[grow] = mx;
    rowinv[grow] = 1.0f / s;
}

// ---------------------------------------------------------------------------
// Fused softmax + AV, barrier-free ownership layout (r9 structure) with
// COALESCED fragment-order vT reads (r11 fix for r9's measured L2
// request-rate ceiling). Block = 16 rows of one batch; 4 waves = 4
// K-quarters (1024 k each). Lane (m,qq) OWNS attn[row m][k=kk*32+qq*8..+8]:
// loads 8 fp32 (64B-chunk granularity), exps (diag bias folded), nt-writes
// fp32 weights back, feeds the same registers to MFMA as its A fragment.
// B fragments are 1KB coalesced wave reads of frag-order vfrag (L2-resident,
// batch pinned to an XCD pair). ZERO barriers in the K-loop; one 3-phase
// LDS reduce at the end sums the 4 K-quarter partials.
// Grid 1024 x 256 thr = 4096 waves = 16 waves/CU free-running.
// ---------------------------------------------------------------------------
__global__ __launch_bounds__(256) void av_softmax_mfma(
    float* __restrict__ attn, const unsigned short* __restrict__ vT,
    const float* __restrict__ rowm, const float* __restrict__ rowinv,
    const unsigned* __restrict__ gmax, float* __restrict__ out)
{
    // block i -> XCD i%8; batch b owns XCDs {2b, 2b+1}
    const int lin = blockIdx.x;
    const int b = (lin & 7) >> 1;
    const int rg = ((lin >> 3) << 1) | (lin & 1);   // 0..255 row-group in batch
    const int rowBase = rg * 16;

    float* A = attn + (size_t)b * SS * SS;
    const unsigned short* Bf = vT + (size_t)b * (16 * 128 * 512);
    const float bias = PIW * fdec(*gmax);

    __shared__ f32x4 redl[2][64][16];   // 32 KB end-of-kernel exchange

    const int tid = threadIdx.x;
    const int lane = tid & 63, w = tid >> 6;     // w = K-quarter
    const int m = lane & 15, qq = lane >> 4;

    const int rr = rowBase + m;                  // my owned A row (in batch)
    float* Arow = A + (size_t)rr * SS;
    const float mr = rowm[b * SS + rr];
    const float ri = rowinv[b * SS + rr];

    f32x4 acc[16];
    #pragma unroll
    for (int n = 0; n < 16; n++)
        acc[n] = (f32x4){0.f, 0.f, 0.f, 0.f};

    const int kq0 = w * (SS / 4);                // my K-quarter base
    const unsigned short* Bfl = Bf + (size_t)lane * 8;

    for (int kk = 0; kk < 32; kk++) {
        const int k0 = kq0 + kk * 32 + qq * 8;   // my 8-wide owned k slice
        f32x4 a0 = *(const f32x4*)&Arow[k0];
        f32x4 a1 = *(const f32x4*)&Arow[k0 + 4];
        float e[8];
        #pragma unroll
        for (int t = 0; t < 8; t++) {
            float x = (t < 4) ? a0[t & 3] : a1[t & 3];
            x += ((k0 + t) == rr) ? bias : 0.0f;
            e[t] = __expf(x - mr) * ri;
        }
        __builtin_nontemporal_store((f32x4){e[0], e[1], e[2], e[3]},
                                    (f32x4*)&Arow[k0]);
        __builtin_nontemporal_store((f32x4){e[4], e[5], e[6], e[7]},
                                    (f32x4*)&Arow[k0 + 4]);
        u16v8 af = (u16v8){f2bf(e[0]), f2bf(e[1]), f2bf(e[2]), f2bf(e[3]),
                           f2bf(e[4]), f2bf(e[5]), f2bf(e[6]), f2bf(e[7])};
        const int kkg = w * 32 + kk;             // global 32-k tile index
        #pragma unroll
        for (int n = 0; n < 16; n++) {
            // coalesced 1KB wave read of frag-order vfrag
            u16v8 bf = *(const u16v8*)&Bfl[((size_t)n * 128 + kkg) * 512];
            acc[n] = mfma_bf16(af, bf, acc[n]);
        }
    }

    // ---- reduce the 4 K-quarter partials (3-phase, 32 KB LDS) ----
    if (w == 1 || w == 3) {
        const int buf = w >> 1;
        #pragma unroll
        for (int n = 0; n < 16; n++)
            redl[buf][lane][n] = acc[n];
    }
    __syncthreads();
    if (w == 0 || w == 2) {
        const int buf = w >> 1;
        #pragma unroll
        for (int n = 0; n < 16; n++)
            acc[n] += redl[buf][lane][n];
    }
    __syncthreads();
    if (w == 2) {
        #pragma unroll
        for (int n = 0; n < 16; n++)
            redl[0][lane][n] = acc[n];
    }
    __syncthreads();
    if (w == 0) {
        #pragma unroll
        for (int n = 0; n < 16; n++) {
            f32x4 o = acc[n] + redl[0][lane][n];
            #pragma unroll
            for (int r = 0; r < 4; r++) {
                int row = rowBase + qq * 4 + r;
                int col = n * 16 + m;
                __builtin_nontemporal_store(
                    o[r], &out[((size_t)b * SS + row) * DD + col]);
            }
        }
    }
}

extern "C" void kernel_launch(void* const* d_in, const int* in_sizes, int n_in,
                              void* d_out, int out_size, void* d_ws, size_t ws_size,
                              hipStream_t stream)
{
    const float* query = (const float*)d_in[0];
    const float* key_  = (const float*)d_in[1];
    const float* value = (const float*)d_in[2];
    const float* Wq    = (const float*)d_in[3];
    const float* Wk    = (const float*)d_in[4];
    const float* Wv    = (const float*)d_in[5];

    float* out  = (float*)d_out;                          // [B,S,D]
    float* attn = out + (size_t)BB * SS * DD;             // [B,S,S]

    const size_t E = (size_t)BB * SS * DD;                // 4.19M elements
    unsigned short* qh = (unsigned short*)d_ws;           // fragment order
    unsigned short* ql = qh + E;
    unsigned short* kh = ql + E;
    unsigned short* kl = kh + E;
    unsigned short* vT = kl + E;                          // fragment order
    float* tmaxg  = (float*)(vT + E);                     // [32][16384]
    float* tsumg  = tmaxg + 32 * (size_t)NROWS;           // [32][16384]
    float* rowm   = tsumg + 32 * (size_t)NROWS;           // [16384]
    float* rowinv = rowm + NROWS;                         // [16384]
    unsigned* gmax = (unsigned*)(rowinv + NROWS);

    // 1) projections via split-bf16 MFMA; fragment-order outputs; gmax init
    proj_kernel<<<dim3(DD / 128, (BB * SS) / 128, 3), 256, 0, stream>>>(
        query, key_, value, Wq, Wk, Wv, qh, ql, kh, kl, vT, gmax);
    // 2) raw scores via split-bf16 MFMA, fragment-direct loads (no LDS),
    //    per-row tile stats + global max
    scores_mfma<<<dim3(4096), 256, 0, stream>>>(
        qh, ql, kh, kl, attn, gmax, tmaxg, tsumg);
    // 3) merge tile stats -> per-row (max, 1/sum) with diag bias
    stats_merge<<<dim3(NROWS / 256), 256, 0, stream>>>(
        tmaxg, tsumg, attn, gmax, rowm, rowinv);
    // 4) fused softmax-normalize (writes fp32 attn output) + attn @ v,
    //    barrier-free K-quarter split
    av_softmax_mfma<<<dim3(1024), 256, 0, stream>>>(
        attn, vT, rowm, rowinv, gmax, out);
}

// Round 16
// 613.126 us; speedup vs baseline: 1.4713x; 1.4713x over previous
//
#include <hip/hip_runtime.h>
#include <cstdint>
#include <cstddef>

// Problem constants
#define BB 4
#define SS 4096
#define DD 256
#define SCORE_SCALE (1.0f/16.0f)   // 1/sqrt(256)
#define PIW 0.5f
#define NROWS (BB * SS)            // 16384 flattened rows

typedef float          f32x4  __attribute__((ext_vector_type(4)));
typedef __bf16         bf16v8 __attribute__((ext_vector_type(8)));
typedef unsigned short u16v8  __attribute__((ext_vector_type(8)));
typedef unsigned short u16v4  __attribute__((ext_vector_type(4)));

__device__ __forceinline__ f32x4 mfma_bf16(u16v8 a, u16v8 b, f32x4 c) {
    return __builtin_amdgcn_mfma_f32_16x16x32_bf16(
        __builtin_bit_cast(bf16v8, a), __builtin_bit_cast(bf16v8, b), c, 0, 0, 0);
}

__device__ __forceinline__ unsigned short f2bf(float f) {
    unsigned u = __float_as_uint(f);
    u += 0x7FFFu + ((u >> 16) & 1u);           // RNE (inputs finite)
    return (unsigned short)(u >> 16);
}
__device__ __forceinline__ float bf2f(unsigned short h) {
    return __uint_as_float(((unsigned)h) << 16);
}
__device__ __forceinline__ unsigned fenc(float x) {
    unsigned u = __float_as_uint(x);
    return (u & 0x80000000u) ? ~u : (u | 0x80000000u);
}
__device__ __forceinline__ float fdec(unsigned e) {
    return __uint_as_float((e & 0x80000000u) ? (e ^ 0x80000000u) : ~e);
}

// MFMA-fragment-order index for a [row][k] bf16 element (16-row x 32-k tiles):
// frag[tile = row>>4][kk = k>>5][lane = (row&15)|(((k>>3)&3)<<4)][e = k&7]
// A wave's fragment load (fixed tile,kk; lane 0..63; e 0..7) is 1KB contiguous.
__device__ __forceinline__ size_t fragidx(int growFlat, int k, int kPerRow32) {
    return ((((size_t)(growFlat >> 4) * kPerRow32 + (k >> 5)) * 64)
            + ((growFlat & 15) | (((k >> 3) & 3) << 4))) * 8 + (k & 7);
}

// ---------------------------------------------------------------------------
// Projections via split-bf16 MFMA (Ah*Wh + Ah*Wl + Al*Wh ~ fp32 precision):
// C = A[16384,256] @ W[256,256]. 128x128 tile, 4 waves (2x2 of 64x64), BK=32.
// z=0: qh/ql bf16 split, FRAGMENT ORDER. z=1: kh/kl same. z=2: vfrag.
// Also inits gmax.  (round-12 proven version)
// ---------------------------------------------------------------------------
#define PSPAD 42   // 32 + 10 u16 row stride (W-transpose staging conflicts)

__global__ __launch_bounds__(256) void proj_kernel(
    const float* __restrict__ query, const float* __restrict__ key_, const float* __restrict__ value,
    const float* __restrict__ Wq, const float* __restrict__ Wk, const float* __restrict__ Wv,
    unsigned short* __restrict__ qh, unsigned short* __restrict__ ql,
    unsigned short* __restrict__ kh, unsigned short* __restrict__ kl,
    unsigned short* __restrict__ vT, unsigned* __restrict__ gmax)
{
    const int z = blockIdx.z;
    const float* A = (z == 0) ? query : (z == 1) ? key_ : value;
    const float* W = (z == 0) ? Wq    : (z == 1) ? Wk   : Wv;
    if (z == 0 && blockIdx.x == 0 && blockIdx.y == 0 && threadIdx.x == 0)
        *gmax = 0x007FFFFFu;   // fenc(-inf)

    __shared__ unsigned short Ah[128][PSPAD];
    __shared__ unsigned short Al[128][PSPAD];
    __shared__ unsigned short Bh[128][PSPAD];   // W^T split: [n][k]
    __shared__ unsigned short Bl[128][PSPAD];

    const int tid = threadIdx.x;
    const int lane = tid & 63, w = tid >> 6;
    const int wr = (w >> 1) * 64, wc = (w & 1) * 64;
    const int m = lane & 15, qq = lane >> 4;
    const int rowBase = blockIdx.y * 128;   // flattened B*S row
    const int colBase = blockIdx.x * 128;

    f32x4 acc[4][4];
    #pragma unroll
    for (int i = 0; i < 4; i++)
        #pragma unroll
        for (int j = 0; j < 4; j++)
            acc[i][j] = (f32x4){0.f, 0.f, 0.f, 0.f};

    const int chunk = (tid & 3) * 8;   // float offset within 32-wide k-slab
    const int srow  = tid >> 2;        // 0..63

    for (int k0 = 0; k0 < DD; k0 += 32) {
        // A staging: rows srow, srow+64; 8 fp32 -> bf16 h/l
        #pragma unroll
        for (int i = 0; i < 2; i++) {
            int r = srow + i * 64;
            const float* src = &A[(size_t)(rowBase + r) * DD + k0 + chunk];
            float4 f0 = *(const float4*)src;
            float4 f1 = *(const float4*)(src + 4);
            float v[8] = {f0.x, f0.y, f0.z, f0.w, f1.x, f1.y, f1.z, f1.w};
            u16v8 h, l;
            #pragma unroll
            for (int e = 0; e < 8; e++) {
                h[e] = f2bf(v[e]);
                l[e] = f2bf(v[e] - bf2f(h[e]));
            }
            *(u16v8*)&Ah[r][chunk] = h;
            *(u16v8*)&Al[r][chunk] = l;
        }
        // W staging transposed: W[k0+kk][colBase+n] -> Bh/Bl[n][kk]
        #pragma unroll
        for (int i = 0; i < 4; i++) {
            int idx = tid + i * 256;
            int kk = idx >> 5, nq = idx & 31;
            float4 f = *(const float4*)&W[(size_t)(k0 + kk) * DD + colBase + nq * 4];
            float v[4] = {f.x, f.y, f.z, f.w};
            #pragma unroll
            for (int e = 0; e < 4; e++) {
                unsigned short h = f2bf(v[e]);
                unsigned short l = f2bf(v[e] - bf2f(h));
                Bh[nq * 4 + e][kk] = h;
                Bl[nq * 4 + e][kk] = l;
            }
        }
        __syncthreads();

        const int kb = qq * 8;
        u16v8 ah[4], al[4], bh[4], bl[4];
        #pragma unroll
        for (int i = 0; i < 4; i++) {
            ah[i] = *(const u16v8*)&Ah[wr + i * 16 + m][kb];
            al[i] = *(const u16v8*)&Al[wr + i * 16 + m][kb];
            bh[i] = *(const u16v8*)&Bh[wc + i * 16 + m][kb];
            bl[i] = *(const u16v8*)&Bl[wc + i * 16 + m][kb];
        }
        #pragma unroll
        for (int i = 0; i < 4; i++)
            #pragma unroll
            for (int j = 0; j < 4; j++) {
                acc[i][j] = mfma_bf16(ah[i], bh[j], acc[i][j]);
                acc[i][j] = mfma_bf16(ah[i], bl[j], acc[i][j]);
                acc[i][j] = mfma_bf16(al[i], bh[j], acc[i][j]);
            }
        __syncthreads();
    }

    // epilogue: lane (m,qq) holds C[rowBase+wr+i*16+qq*4+r][colBase+wc+j*16+m]
    #pragma unroll
    for (int i = 0; i < 4; i++) {
        #pragma unroll
        for (int j = 0; j < 4; j++) {
            #pragma unroll
            for (int r = 0; r < 4; r++) {
                const int gr  = rowBase + wr + i * 16 + qq * 4 + r;
                const int col = colBase + wc + j * 16 + m;
                const float v = acc[i][j][r];
                if (z == 2) {
                    const int b2 = gr >> 12, s2 = gr & (SS - 1);
                    size_t idx = (size_t)b2 * (16 * 128 * 512)
                               + fragidx(col, s2, 128);
                    vT[idx] = f2bf(v);
                } else {
                    unsigned short h = f2bf(v);
                    unsigned short l = f2bf(v - bf2f(h));
                    unsigned short* H = (z == 0) ? qh : kh;
                    unsigned short* L = (z == 0) ? ql : kl;
                    size_t idx = fragidx(gr, col, 8);   // tiles over B*S rows
                    H[idx] = h;
                    L[idx] = l;
                }
            }
        }
    }
}

// ---------------------------------------------------------------------------
// Scores: C = (q@k^T)/16 via split-bf16 MFMA: qh*kh + qh*kl + ql*kh.
// 128x128 C-tile, 4 waves (2x2 of 64x64). Fragment-order panels: coalesced
// 1KB wave loads straight from the L2-resident panels — NO LDS staging, NO
// K-loop barriers, compiler-scheduled (round-12 proven). Epilogue: per-row
// tile stats -> tmaxg/tsumg, block max -> gmax, then nt C-stores last.
// ---------------------------------------------------------------------------
__global__ __launch_bounds__(256) void scores_mfma(
    const unsigned short* __restrict__ qh, const unsigned short* __restrict__ ql,
    const unsigned short* __restrict__ kh, const unsigned short* __restrict__ kl,
    float* __restrict__ attn, unsigned* __restrict__ gmax,
    float* __restrict__ tmaxg, float* __restrict__ tsumg)
{
    // XCD decode: block i -> XCD i%8; batch b owns XCDs {2b,2b+1}
    const int lin = blockIdx.x;
    const int b = (lin & 7) >> 1;
    const int t2 = ((lin >> 3) << 1) | (lin & 1);   // 0..1023
    const int bx = t2 & 31, by = t2 >> 5;
    const int rowBase = by * 128;
    const int colBase = bx * 128;

    float* C = attn + (size_t)b * SS * SS;

    __shared__ float s_m[4][64];
    __shared__ float s_s[4][64];
    __shared__ float red[128];

    const int tid = threadIdx.x;
    const int lane = tid & 63, w = tid >> 6;
    const int wr = (w >> 1) * 64, wc = (w & 1) * 64;
    const int m = lane & 15, qq = lane >> 4;

    f32x4 acc[4][4];
    #pragma unroll
    for (int i = 0; i < 4; i++)
        #pragma unroll
        for (int j = 0; j < 4; j++)
            acc[i][j] = (f32x4){0.f, 0.f, 0.f, 0.f};

    const size_t ta = ((size_t)b * SS + rowBase + wr) >> 4;
    const size_t tb = ((size_t)b * SS + colBase + wc) >> 4;

    #pragma unroll 2
    for (int kk = 0; kk < 8; kk++) {
        u16v8 ah[4], al[4], bh[4], bl[4];
        #pragma unroll
        for (int i = 0; i < 4; i++) {
            const size_t fa = (((ta + i) * 8 + kk) * 64 + lane) * 8;
            const size_t fb = (((tb + i) * 8 + kk) * 64 + lane) * 8;
            ah[i] = *(const u16v8*)&qh[fa];   // 1KB coalesced per wave
            al[i] = *(const u16v8*)&ql[fa];
            bh[i] = *(const u16v8*)&kh[fb];
            bl[i] = *(const u16v8*)&kl[fb];
        }
        #pragma unroll
        for (int i = 0; i < 4; i++)
            #pragma unroll
            for (int j = 0; j < 4; j++) {
                acc[i][j] = mfma_bf16(ah[i], bh[j], acc[i][j]);
                acc[i][j] = mfma_bf16(ah[i], bl[j], acc[i][j]);
                acc[i][j] = mfma_bf16(al[i], bh[j], acc[i][j]);
            }
    }

    // scale once; all consumers (stats, gmax, C store) use scaled values
    #pragma unroll
    for (int i = 0; i < 4; i++)
        #pragma unroll
        for (int j = 0; j < 4; j++)
            acc[i][j] *= SCORE_SCALE;

    // ---- per-row tile stats (flash-style), register resident ----
    float lmax[16];
    #pragma unroll
    for (int i = 0; i < 4; i++)
        #pragma unroll
        for (int r = 0; r < 4; r++)
            lmax[i * 4 + r] = fmaxf(fmaxf(acc[i][0][r], acc[i][1][r]),
                                    fmaxf(acc[i][2][r], acc[i][3][r]));
    #pragma unroll
    for (int t = 0; t < 16; t++) {
        #pragma unroll
        for (int msk = 1; msk < 16; msk <<= 1)
            lmax[t] = fmaxf(lmax[t], __shfl_xor(lmax[t], msk));
    }
    if (m == 0) {
        #pragma unroll
        for (int i = 0; i < 4; i++)
            #pragma unroll
            for (int r = 0; r < 4; r++)
                s_m[w][i * 16 + qq * 4 + r] = lmax[i * 4 + r];
    }
    __syncthreads();
    float lsum[16];
    #pragma unroll
    for (int i = 0; i < 4; i++)
        #pragma unroll
        for (int r = 0; r < 4; r++) {
            int idx = i * 16 + qq * 4 + r;
            float rm = fmaxf(s_m[w][idx], s_m[w ^ 1][idx]);
            float s = 0.f;
            #pragma unroll
            for (int j = 0; j < 4; j++)
                s += __expf(acc[i][j][r] - rm);
            lsum[i * 4 + r] = s;
        }
    #pragma unroll
    for (int t = 0; t < 16; t++) {
        #pragma unroll
        for (int msk = 1; msk < 16; msk <<= 1)
            lsum[t] += __shfl_xor(lsum[t], msk);
    }
    if (m == 0) {
        #pragma unroll
        for (int i = 0; i < 4; i++)
            #pragma unroll
            for (int r = 0; r < 4; r++)
                s_s[w][i * 16 + qq * 4 + r] = lsum[i * 4 + r];
    }
    __syncthreads();

    if (tid < 128) {
        int wp = tid >> 6, lr = tid & 63;
        float tm = fmaxf(s_m[2 * wp][lr], s_m[2 * wp + 1][lr]);
        float ts = s_s[2 * wp][lr] + s_s[2 * wp + 1][lr];   // same reference max
        size_t gi = (size_t)bx * NROWS + (size_t)b * SS + rowBase + tid;
        tmaxg[gi] = tm;
        tsumg[gi] = ts;
        red[tid] = tm;
    }
    __syncthreads();
    for (int s2 = 64; s2 > 0; s2 >>= 1) {
        if (tid < s2) red[tid] = fmaxf(red[tid], red[tid + s2]);
        __syncthreads();
    }
    if (tid == 0) atomicMax(gmax, fenc(red[0]));

    // store raw scores LAST (nt stream; no barrier after -> no drain stall)
    #pragma unroll
    for (int i = 0; i < 4; i++)
        #pragma unroll
        for (int j = 0; j < 4; j++)
            #pragma unroll
            for (int r = 0; r < 4; r++) {
                int row = rowBase + wr + i * 16 + qq * 4 + r;
                int col = colBase + wc + j * 16 + m;
                __builtin_nontemporal_store(acc[i][j][r], &C[(size_t)row * SS + col]);
            }
}

// ---------------------------------------------------------------------------
// Merge per-tile stats into per-row (max, 1/sum), folding in the diag bias
// (needs final gmax). Reads 4 MB stats + 16K diag elements. Tiny.
// ---------------------------------------------------------------------------
__global__ __launch_bounds__(256) void stats_merge(
    const float* __restrict__ tmaxg, const float* __restrict__ tsumg,
    const float* __restrict__ attn, const unsigned* __restrict__ gmax,
    float* __restrict__ rowm, float* __restrict__ rowinv)
{
    const int grow = blockIdx.x * 256 + threadIdx.x;   // 0..16383
    const int b = grow >> 12, i = grow & (SS - 1);
    const float bias = PIW * fdec(*gmax);

    float tm[32];
    float mx = -INFINITY;
    #pragma unroll
    for (int t = 0; t < 32; t++) {
        tm[t] = tmaxg[(size_t)t * NROWS + grow];
        mx = fmaxf(mx, tm[t]);
    }
    const float dii = attn[(size_t)b * SS * SS + (size_t)i * SS + i];
    mx = fmaxf(mx, dii + bias);

    float s = 0.f;
    #pragma unroll
    for (int t = 0; t < 32; t++)
        s += tsumg[(size_t)t * NROWS + grow] * __expf(tm[t] - mx);
    // replace unbiased diag contribution with biased one
    s += __expf(dii + bias - mx) - __expf(dii - mx);

    rowm[grow] = mx;
    rowinv[grow] = 1.0f / s;
}

// ---------------------------------------------------------------------------
// Fused softmax + AV. BM=32, BN=256, BK=256 (16 fat steps). Grid 512
// (batch pinned to an XCD pair). Per step: 8 f32x4 raw-score loads in
// flight, exp (diag bias folded), nt fp32 weight writeback, bf16 LDS stage
// as 16B writes. B fragments from fragment-order vfrag: coalesced 1KB wave
// reads. One __syncthreads per 256-wide K step. (round-14 proven)
// ---------------------------------------------------------------------------
#define AVBK 256
#define ASW 272   // u16 row stride (544B: 16B-aligned)

__global__ __launch_bounds__(256) void av_softmax_mfma(
    float* __restrict__ attn, const unsigned short* __restrict__ vT,
    const float* __restrict__ rowm, const float* __restrict__ rowinv,
    const unsigned* __restrict__ gmax, float* __restrict__ out)
{
    // block i -> XCD i%8; batch b owns XCDs {2b, 2b+1}
    const int lin = blockIdx.x;
    const int b = (lin & 7) >> 1;
    const int rowTile = ((lin >> 3) << 1) | (lin & 1);   // 0..127
    const int rowBase = rowTile * 32;

    float* A = attn + (size_t)b * SS * SS;
    const unsigned short* Bf = vT + (size_t)b * (16 * 128 * 512);
    const float bias = PIW * fdec(*gmax);

    __shared__ __align__(16) unsigned short As[2][32][ASW];

    const int tid = threadIdx.x;
    const int lane = tid & 63, w = tid >> 6;
    const int m = lane & 15, qq = lane >> 4;

    // A-staging map: thread owns row ra, col groups g*64 + c8*8 .. +8
    const int ra = tid >> 3;              // 0..31
    const int c8 = tid & 7;               // 0..7
    const int rr = rowBase + ra;
    float* Arow = A + (size_t)rr * SS;
    const float mr = rowm[b * SS + rr];
    const float ri = rowinv[b * SS + rr];

    f32x4 acc[2][4];
    #pragma unroll
    for (int i = 0; i < 2; i++)
        #pragma unroll
        for (int j = 0; j < 4; j++)
            acc[i][j] = (f32x4){0.f, 0.f, 0.f, 0.f};

    f32x4 pf[8];   // 8 float4 per thread in flight per step

    auto loadA = [&](int kbase) {
        #pragma unroll
        for (int g = 0; g < 4; g++) {
            pf[2 * g]     = *(const f32x4*)&Arow[kbase + g * 64 + c8 * 8];
            pf[2 * g + 1] = *(const f32x4*)&Arow[kbase + g * 64 + c8 * 8 + 4];
        }
    };
    // exp-normalize pf, nt fp32 writeback, one 16B bf16 LDS write per group
    auto procStore = [&](int kbase, int buf) {
        #pragma unroll
        for (int g = 0; g < 4; g++) {
            int c = g * 64 + c8 * 8;
            int j0 = kbase + c;
            float wv[8];
            #pragma unroll
            for (int e = 0; e < 8; e++) {
                float x = (e < 4) ? pf[2 * g][e] : pf[2 * g + 1][e & 3];
                x += ((j0 + e) == rr) ? bias : 0.0f;
                wv[e] = __expf(x - mr) * ri;
            }
            __builtin_nontemporal_store((f32x4){wv[0], wv[1], wv[2], wv[3]},
                                        (f32x4*)&Arow[j0]);
            __builtin_nontemporal_store((f32x4){wv[4], wv[5], wv[6], wv[7]},
                                        (f32x4*)&Arow[j0 + 4]);
            *(u16v8*)&As[buf][ra][c] =
                (u16v8){f2bf(wv[0]), f2bf(wv[1]), f2bf(wv[2]), f2bf(wv[3]),
                        f2bf(wv[4]), f2bf(wv[5]), f2bf(wv[6]), f2bf(wv[7])};
        }
    };

    const int NT = SS / AVBK;   // 16 K-steps

    loadA(0);
    procStore(0, 0);
    __syncthreads();

    for (int t = 0; t < NT; t++) {
        const int k0 = t * AVBK;
        const int cur = t & 1;
        if (t + 1 < NT)
            loadA(k0 + AVBK);           // 8 loads in flight across MFMA phase
        #pragma unroll
        for (int kk = 0; kk < 8; kk++) {
            const int kb = kk * 32 + qq * 8;
            const int kkg = (k0 >> 5) + kk;          // global 32-k tile index
            u16v8 bf_[4], af_[2];
            #pragma unroll
            for (int j = 0; j < 4; j++)              // coalesced 1KB/wave reads
                bf_[j] = *(const u16v8*)&Bf[(((size_t)(w * 4 + j) * 128 + kkg) * 64 + lane) * 8];
            #pragma unroll
            for (int i = 0; i < 2; i++)
                af_[i] = *(const u16v8*)&As[cur][i * 16 + m][kb];
            #pragma unroll
            for (int i = 0; i < 2; i++)
                #pragma unroll
                for (int j = 0; j < 4; j++)
                    acc[i][j] = mfma_bf16(af_[i], bf_[j], acc[i][j]);
        }
        if (t + 1 < NT) {
            procStore(k0 + AVBK, cur ^ 1);
            __syncthreads();
        }
    }

    #pragma unroll
    for (int i = 0; i < 2; i++) {
        #pragma unroll
        for (int j = 0; j < 4; j++) {
            #pragma unroll
            for (int r = 0; r < 4; r++) {
                int row = rowBase + i * 16 + qq * 4 + r;
                int col = w * 64 + j * 16 + m;
                __builtin_nontemporal_store(
                    acc[i][j][r], &out[((size_t)b * SS + row) * DD + col]);
            }
        }
    }
}

extern "C" void kernel_launch(void* const* d_in, const int* in_sizes, int n_in,
                              void* d_out, int out_size, void* d_ws, size_t ws_size,
                              hipStream_t stream)
{
    const float* query = (const float*)d_in[0];
    const float* key_  = (const float*)d_in[1];
    const float* value = (const float*)d_in[2];
    const float* Wq    = (const float*)d_in[3];
    const float* Wk    = (const float*)d_in[4];
    const float* Wv    = (const float*)d_in[5];

    float* out  = (float*)d_out;                          // [B,S,D]
    float* attn = out + (size_t)BB * SS * DD;             // [B,S,S]

    const size_t E = (size_t)BB * SS * DD;                // 4.19M elements
    unsigned short* qh = (unsigned short*)d_ws;           // fragment order
    unsigned short* ql = qh + E;
    unsigned short* kh = ql + E;
    unsigned short* kl = kh + E;
    unsigned short* vT = kl + E;                          // fragment order
    float* tmaxg  = (float*)(vT + E);                     // [32][16384]
    float* tsumg  = tmaxg + 32 * (size_t)NROWS;           // [32][16384]
    float* rowm   = tsumg + 32 * (size_t)NROWS;           // [16384]
    float* rowinv = rowm + NROWS;                         // [16384]
    unsigned* gmax = (unsigned*)(rowinv + NROWS);

    // 1) projections via split-bf16 MFMA; fragment-order outputs; gmax init
    proj_kernel<<<dim3(DD / 128, (BB * SS) / 128, 3), 256, 0, stream>>>(
        query, key_, value, Wq, Wk, Wv, qh, ql, kh, kl, vT, gmax);
    // 2) raw scores via split-bf16 MFMA, fragment-direct loads (no LDS),
    //    per-row tile stats + global max
    scores_mfma<<<dim3(4096), 256, 0, stream>>>(
        qh, ql, kh, kl, attn, gmax, tmaxg, tsumg);
    // 3) merge tile stats -> per-row (max, 1/sum) with diag bias
    stats_merge<<<dim3(NROWS / 256), 256, 0, stream>>>(
        tmaxg, tsumg, attn, gmax, rowm, rowinv);
    // 4) fused softmax-normalize (writes fp32 attn output) + attn @ v
    av_softmax_mfma<<<dim3(512), 256, 0, stream>>>(
        attn, vT, rowm, rowinv, gmax, out);
}